// Round 4
// baseline (7207.521 us; speedup 1.0000x reference)
//
#include <hip/hip_runtime.h>
#include <hip/hip_bf16.h>

#define BB 8
#define NN 2048
#define KK 20
#define BN (BB*NN)
#define MSPLIT 4
#define RSQ 0.99999500003749969f   // 1/sqrt(1+1e-5)

// ---------------- workspace layout (float-slot units), 44.3 MiB total ----------------
constexpr size_t OFF_X1  = 0;                          // BN*64
constexpr size_t OFF_X2  = OFF_X1  + (size_t)BN*64;    // BN*64
constexpr size_t OFF_X3  = OFF_X2  + (size_t)BN*64;    // BN*128
constexpr size_t OFF_X4  = OFF_X3  + (size_t)BN*128;   // BN*256
constexpr size_t OFF_XX  = OFF_X4  + (size_t)BN*256;   // BN
constexpr size_t OFF_SC  = OFF_XX  + BN;               // scratch: (pv,pi) then (q,bs), BN*160
constexpr size_t OFF_ID  = OFF_SC  + (size_t)BN*160;   // int BN*20
constexpr size_t OFF_W5T = OFF_ID  + (size_t)BN*20;    // 512*512, [c][o]
constexpr size_t OFF_MX  = OFF_W5T + 512*512;          // uint B*512
constexpr size_t OFF_MN  = OFF_MX  + BB*512;
constexpr size_t WS_END  = OFF_MN  + BB*512;           // 11,624,448 floats

__device__ inline unsigned encf(float f){ unsigned u=__float_as_uint(f); return (u&0x80000000u)? ~u : (u|0x80000000u); }
__device__ inline float decf(unsigned e){ unsigned u=(e&0x80000000u)? (e&0x7fffffffu) : ~e; return __uint_as_float(u); }
__device__ inline float lrelu(float h){ return h>=0.f ? h : 0.2f*h; }

// ---------------- init ----------------
__global__ void transposeW5_k(const float* s, float* d){
  int i = blockIdx.x*256 + threadIdx.x;   // 262144
  int o = i>>9, c = i&511;
  d[c*512+o] = s[i];
}
__global__ void init_enc_k(unsigned* mx, unsigned* mn){
  int i = blockIdx.x*256 + threadIdx.x;   // 4096
  mx[i] = 0x007FFFFFu;   // enc(-inf)
  mn[i] = 0xFF800000u;   // enc(+inf)
}

// ---------------- KNN ----------------
template<int C>
__launch_bounds__(256) __global__ void sqnorm_k(const float* X, float* xx){
  int i = blockIdx.x*256 + threadIdx.x;   // BN
  const float* r = X + (size_t)i*C;
  float s = 0.f;
  #pragma unroll
  for(int c=0;c<C;c++) s = fmaf(r[c], r[c], s);
  xx[i] = s;
}

template<int C>
__launch_bounds__(256) __global__ void knn_part_k(const float* X, const float* xx,
                                                  float* pval, int* pidx){
  const int b = blockIdx.y;
  const int n = blockIdx.x*256 + threadIdx.x;
  const float* Xb = X + (size_t)b*NN*C;
  float xn[C];
  if constexpr (C % 4 == 0){
    #pragma unroll
    for(int c=0;c<C;c+=4){ float4 v = *(const float4*)(Xb + (size_t)n*C + c);
      xn[c]=v.x; xn[c+1]=v.y; xn[c+2]=v.z; xn[c+3]=v.w; }
  } else {
    #pragma unroll
    for(int c=0;c<C;c++) xn[c] = Xb[(size_t)n*C + c];
  }
  const float xxn = xx[b*NN+n];
  const float* xxb = xx + b*NN;
  float val[KK]; int ind[KK];
  #pragma unroll
  for(int j=0;j<KK;j++){ val[j] = -INFINITY; ind[j] = 0; }
  const int m0 = blockIdx.z*(NN/MSPLIT);
  for(int m=m0; m<m0+NN/MSPLIT; ++m){
    float s = 0.f;
    if constexpr (C % 4 == 0){
      const float4* xm4 = (const float4*)(Xb + (size_t)m*C);
      #pragma unroll
      for(int c4=0;c4<C/4;c4++){
        float4 v = xm4[c4];
        s = fmaf(xn[4*c4+0], v.x, s); s = fmaf(xn[4*c4+1], v.y, s);
        s = fmaf(xn[4*c4+2], v.z, s); s = fmaf(xn[4*c4+3], v.w, s);
      }
    } else {
      const float* xm = Xb + (size_t)m*C;
      #pragma unroll
      for(int c=0;c<C;c++) s = fmaf(xn[c], xm[c], s);
    }
    float negd = (2.f*s - xxn) - xxb[m];
    if (negd > val[KK-1]){
      float cv = negd; int ci = m;
      #pragma unroll
      for(int j=0;j<KK;j++){
        if (cv > val[j]){ float tv=val[j]; int ti=ind[j]; val[j]=cv; ind[j]=ci; cv=tv; ci=ti; }
      }
    }
  }
  float* pv = pval + (((size_t)(b*NN+n))*MSPLIT + blockIdx.z)*KK;
  int*   pi = pidx + (((size_t)(b*NN+n))*MSPLIT + blockIdx.z)*KK;
  #pragma unroll
  for(int j=0;j<KK;j++){ pv[j]=val[j]; pi[j]=ind[j]; }
}

__launch_bounds__(256) __global__ void knn_merge_k(const float* pval, const int* pidx, int* idx){
  int i = blockIdx.x*256 + threadIdx.x;   // BN
  const float* pv = pval + (size_t)i*MSPLIT*KK;
  const int*   pi = pidx + (size_t)i*MSPLIT*KK;
  int* out = idx + (size_t)i*KK;
  int h0=0,h1=0,h2=0,h3=0;
  for(int j=0;j<KK;j++){
    float bv=-INFINITY; int bi=0x7fffffff; int bl=-1;
    if(h0<KK){ float v=pv[h0];      int ii=pi[h0];      if(v>bv||(v==bv&&ii<bi)){bv=v;bi=ii;bl=0;} }
    if(h1<KK){ float v=pv[KK+h1];   int ii=pi[KK+h1];   if(v>bv||(v==bv&&ii<bi)){bv=v;bi=ii;bl=1;} }
    if(h2<KK){ float v=pv[2*KK+h2]; int ii=pi[2*KK+h2]; if(v>bv||(v==bv&&ii<bi)){bv=v;bi=ii;bl=2;} }
    if(h3<KK){ float v=pv[3*KK+h3]; int ii=pi[3*KK+h3]; if(v>bv||(v==bv&&ii<bi)){bv=v;bi=ii;bl=3;} }
    out[j]=bi;
    if(bl==0)h0++; else if(bl==1)h1++; else if(bl==2)h2++; else h3++;
  }
}

// ---------------- per-64-column qp + gather ----------------
// q[row,oi] = x_row . W[cb+oi, 0:CIN]; bs = (x_row . W[cb+oi, CIN:2CIN]) - q
template<int CIN>
__launch_bounds__(256) __global__ void qp64_k(const float* X, const float* W, int cb,
                                              float* q, float* bs){
  const int t   = blockIdx.x*256 + threadIdx.x;  // BN*8
  const int row = t >> 3;
  const int c0  = (t & 7) * 8;
  float xn[CIN];
  if constexpr (CIN % 4 == 0){
    #pragma unroll
    for(int c=0;c<CIN;c+=4){ float4 v = *(const float4*)(X + (size_t)row*CIN + c);
      xn[c]=v.x; xn[c+1]=v.y; xn[c+2]=v.z; xn[c+3]=v.w; }
  } else {
    #pragma unroll
    for(int c=0;c<CIN;c++) xn[c] = X[(size_t)row*CIN + c];
  }
  for(int oi=c0; oi<c0+8; oi++){
    const float* w = W + (size_t)(cb+oi)*2*CIN;
    float aq=0.f, ap=0.f;
    #pragma unroll
    for(int c=0;c<CIN;c++){ aq = fmaf(xn[c], w[c], aq); ap = fmaf(xn[c], w[CIN+c], ap); }
    q [(size_t)row*64 + oi] = aq;
    bs[(size_t)row*64 + oi] = ap - aq;
  }
}

template<int CFULL>
__launch_bounds__(256) __global__ void gather64_k(const float* q, const float* bs, const int* idx,
    const float* g, const float* bb, int cb, float* out){
  const int t  = blockIdx.x*256 + threadIdx.x;   // BN*64
  const int o  = t & 63;
  const int bn = t >> 6;
  const int b  = bn >> 11;
  const int* id = idx + (size_t)bn*KK;
  float base = bs[t];
  float mx = -INFINITY, mn = INFINITY;
  #pragma unroll
  for(int k=0;k<KK;k++){
    int ik = id[k];
    float v = q[((size_t)((b<<11) + ik))*64 + o];
    mx = fmaxf(mx, v); mn = fminf(mn, v);
  }
  float a  = g[cb+o] * RSQ;
  float bo = bb[cb+o];
  float h  = lrelu((a >= 0.f ? a*(mx+base) : a*(mn+base)) + bo);
  out[(size_t)bn*CFULL + cb + o] = h;
}

// ---------------- head: cat*W5^T with fused max/min over n ----------------
// LDS = 16*512*4 + 2*512*4 = 36864 B
__launch_bounds__(256) __global__ void w5max_k(const float* x1,const float* x2,const float* x3,
    const float* x4, const float* W5T, unsigned* mxe, unsigned* mne){
  __shared__ float cat[16*512];
  __shared__ float redm[512], redn[512];
  const int blk = blockIdx.x;             // 1024 = B * (N/16)
  const int b  = blk >> 7;
  const int r0 = (blk & 127)*16;
  const int t  = threadIdx.x;
  const size_t bn0 = (size_t)b*NN + r0;
  for(int i=t; i<16*512; i+=256){
    int r = i>>9, c = i&511;
    size_t row = bn0 + r;
    float v;
    if(c<64)       v = x1[row*64  + c];
    else if(c<128) v = x2[row*64  + (c-64)];
    else if(c<256) v = x3[row*128 + (c-128)];
    else           v = x4[row*256 + (c-256)];
    cat[i] = v;
  }
  __syncthreads();
  const int half = t>>7, tq = t&127;
  const int rbase = half*8;
  float acc[4][8];
  #pragma unroll
  for(int j=0;j<4;j++)
    #pragma unroll
    for(int r=0;r<8;r++) acc[j][r]=0.f;
  for(int c=0;c<512;c+=4){
    float w[4][4];
    #pragma unroll
    for(int cc=0;cc<4;cc++)
      #pragma unroll
      for(int j=0;j<4;j++) w[cc][j] = W5T[(size_t)(c+cc)*512 + tq + 128*j];
    #pragma unroll
    for(int r=0;r<8;r++){
      float4 cv = *(const float4*)&cat[(rbase+r)*512 + c];
      #pragma unroll
      for(int j=0;j<4;j++)
        acc[j][r] = fmaf(cv.x, w[0][j], fmaf(cv.y, w[1][j], fmaf(cv.z, w[2][j], fmaf(cv.w, w[3][j], acc[j][r]))));
    }
  }
  float lmx[4], lmn[4];
  #pragma unroll
  for(int j=0;j<4;j++){
    float M=-INFINITY, m=INFINITY;
    #pragma unroll
    for(int r=0;r<8;r++){ M=fmaxf(M,acc[j][r]); m=fminf(m,acc[j][r]); }
    lmx[j]=M; lmn[j]=m;
  }
  if(half==0){
    #pragma unroll
    for(int j=0;j<4;j++){ redm[tq+128*j]=lmx[j]; redn[tq+128*j]=lmn[j]; }
  }
  __syncthreads();
  if(half==1){
    #pragma unroll
    for(int j=0;j<4;j++){
      int o = tq + 128*j;
      float M = fmaxf(lmx[j], redm[o]);
      float m = fminf(lmn[j], redn[o]);
      atomicMax(&mxe[b*512+o], encf(M));
      atomicMin(&mne[b*512+o], encf(m));
    }
  }
}

__launch_bounds__(256) __global__ void final_k(const unsigned* mxe, const unsigned* mne,
    const float* g5, const float* b5, const float* Wemb, float* out){
  const int b = blockIdx.x, t = threadIdx.x;
  __shared__ float h[512];
  for(int o=t; o<512; o+=256){
    float mx = decf(mxe[b*512+o]);
    float mn = decf(mne[b*512+o]);
    float a  = g5[o] * RSQ;
    float bo = b5[o];
    float hv = lrelu((a >= 0.f ? a*mx : a*mn) + bo);
    h[o] = hv;
    out[b*512+o] = hv;                       // feat (B,1,512)
  }
  __syncthreads();
  const float* wr = Wemb + (size_t)t*512;
  float s = 0.f;
  for(int o=0;o<512;o+=4){
    float4 w4 = *(const float4*)(wr+o);
    s = fmaf(h[o],w4.x, fmaf(h[o+1],w4.y, fmaf(h[o+2],w4.z, fmaf(h[o+3],w4.w, s))));
  }
  out[4096 + b*256 + t] = s;                 // embedding (B,256)
}

// ---------------- launch ----------------
extern "C" void kernel_launch(void* const* d_in, const int* in_sizes, int n_in,
                              void* d_out, int out_size, void* d_ws, size_t ws_size,
                              hipStream_t stream) {
  // diagnostic guard: if ws too small, write nothing -> absmax would read 4.4375
  if (ws_size < WS_END * sizeof(float)) return;

  const float* x0   = (const float*)d_in[0];
  const float* W1   = (const float*)d_in[1];
  const float* g1   = (const float*)d_in[2];
  const float* b1   = (const float*)d_in[3];
  const float* W2   = (const float*)d_in[4];
  const float* g2   = (const float*)d_in[5];
  const float* b2   = (const float*)d_in[6];
  const float* W3   = (const float*)d_in[7];
  const float* g3   = (const float*)d_in[8];
  const float* b3   = (const float*)d_in[9];
  const float* W4   = (const float*)d_in[10];
  const float* g4   = (const float*)d_in[11];
  const float* b4   = (const float*)d_in[12];
  const float* W5   = (const float*)d_in[13];
  const float* g5   = (const float*)d_in[14];
  const float* b5   = (const float*)d_in[15];
  const float* Wemb = (const float*)d_in[16];

  float* ws = (float*)d_ws;
  float* x1 = ws + OFF_X1;  float* x2 = ws + OFF_X2;
  float* x3 = ws + OFF_X3;  float* x4 = ws + OFF_X4;
  float* xx = ws + OFF_XX;
  // scratch time-sharing: (pv,pi) live knn_part..knn_merge; (q,bs) live qp64..gather64
  float* pv = ws + OFF_SC;
  int*   pi = (int*)(ws + OFF_SC + (size_t)BN*80);
  float* q  = ws + OFF_SC;
  float* bs = ws + OFF_SC + (size_t)BN*64;
  int*   id = (int*)(ws + OFF_ID);
  float* W5Tf = ws + OFF_W5T;
  unsigned* mxe = (unsigned*)(ws + OFF_MX);
  unsigned* mne = (unsigned*)(ws + OFF_MN);
  float* out = (float*)d_out;

  transposeW5_k<<<262144/256,256,0,stream>>>(W5, W5Tf);
  init_enc_k<<<BB*512/256,256,0,stream>>>(mxe, mne);

  dim3 kgrid(NN/256, BB, MSPLIT);

  // layer 1 (3 -> 64)
  sqnorm_k<3><<<BN/256,256,0,stream>>>(x0, xx);
  knn_part_k<3><<<kgrid,256,0,stream>>>(x0, xx, pv, pi);
  knn_merge_k<<<BN/256,256,0,stream>>>(pv, pi, id);
  qp64_k<3><<<BN*8/256,256,0,stream>>>(x0, W1, 0, q, bs);
  gather64_k<64><<<BN*64/256,256,0,stream>>>(q, bs, id, g1, b1, 0, x1);

  // layer 2 (64 -> 64)
  sqnorm_k<64><<<BN/256,256,0,stream>>>(x1, xx);
  knn_part_k<64><<<kgrid,256,0,stream>>>(x1, xx, pv, pi);
  knn_merge_k<<<BN/256,256,0,stream>>>(pv, pi, id);
  qp64_k<64><<<BN*8/256,256,0,stream>>>(x1, W2, 0, q, bs);
  gather64_k<64><<<BN*64/256,256,0,stream>>>(q, bs, id, g2, b2, 0, x2);

  // layer 3 (64 -> 128)
  sqnorm_k<64><<<BN/256,256,0,stream>>>(x2, xx);
  knn_part_k<64><<<kgrid,256,0,stream>>>(x2, xx, pv, pi);
  knn_merge_k<<<BN/256,256,0,stream>>>(pv, pi, id);
  for(int cb=0; cb<128; cb+=64){
    qp64_k<64><<<BN*8/256,256,0,stream>>>(x2, W3, cb, q, bs);
    gather64_k<128><<<BN*64/256,256,0,stream>>>(q, bs, id, g3, b3, cb, x3);
  }

  // layer 4 (128 -> 256)
  sqnorm_k<128><<<BN/256,256,0,stream>>>(x3, xx);
  knn_part_k<128><<<kgrid,256,0,stream>>>(x3, xx, pv, pi);
  knn_merge_k<<<BN/256,256,0,stream>>>(pv, pi, id);
  for(int cb=0; cb<256; cb+=64){
    qp64_k<128><<<BN*8/256,256,0,stream>>>(x3, W4, cb, q, bs);
    gather64_k<256><<<BN*64/256,256,0,stream>>>(q, bs, id, g4, b4, cb, x4);
  }

  // head
  w5max_k<<<BB*(NN/16),256,0,stream>>>(x1, x2, x3, x4, W5Tf, mxe, mne);
  final_k<<<BB,256,0,stream>>>(mxe, mne, g5, b5, Wemb, out);
}

// Round 5
// 5737.050 us; speedup vs baseline: 1.2563x; 1.2563x over previous
//
#include <hip/hip_runtime.h>
#include <hip/hip_bf16.h>

#define BB 8
#define NN 2048
#define KK 20
#define BN (BB*NN)
#define MSPLIT 8
#define RSQ 0.99999500003749969f   // 1/sqrt(1+1e-5)

// ---------------- workspace layout (float-slot units), 44.3 MiB total ----------------
constexpr size_t OFF_X1  = 0;                          // BN*64
constexpr size_t OFF_X2  = OFF_X1  + (size_t)BN*64;    // BN*64
constexpr size_t OFF_X3  = OFF_X2  + (size_t)BN*64;    // BN*128
constexpr size_t OFF_X4  = OFF_X3  + (size_t)BN*128;   // BN*256 (pv/pi alias here during knn)
constexpr size_t OFF_XX  = OFF_X4  + (size_t)BN*256;   // BN
constexpr size_t OFF_SC  = OFF_XX  + BN;               // scratch: q,bs (BN*128 of BN*160)
constexpr size_t OFF_ID  = OFF_SC  + (size_t)BN*160;   // int BN*20
constexpr size_t OFF_W5T = OFF_ID  + (size_t)BN*20;    // 512*512, [c][o]
constexpr size_t OFF_MX  = OFF_W5T + 512*512;          // uint B*512
constexpr size_t OFF_MN  = OFF_MX  + BB*512;
constexpr size_t WS_END  = OFF_MN  + BB*512;           // 11,624,448 floats

__device__ inline unsigned encf(float f){ unsigned u=__float_as_uint(f); return (u&0x80000000u)? ~u : (u|0x80000000u); }
__device__ inline float decf(unsigned e){ unsigned u=(e&0x80000000u)? (e&0x7fffffffu) : ~e; return __uint_as_float(u); }
__device__ inline float lrelu(float h){ return h>=0.f ? h : 0.2f*h; }

// ---------------- init ----------------
__global__ void transposeW5_k(const float* s, float* d){
  int i = blockIdx.x*256 + threadIdx.x;   // 262144
  int o = i>>9, c = i&511;
  d[c*512+o] = s[i];
}
__global__ void init_enc_k(unsigned* mx, unsigned* mn){
  int i = blockIdx.x*256 + threadIdx.x;   // 4096
  mx[i] = 0x007FFFFFu;   // enc(-inf)
  mn[i] = 0xFF800000u;   // enc(+inf)
}

// ---------------- KNN ----------------
template<int C>
__launch_bounds__(256) __global__ void sqnorm_k(const float* X, float* xx){
  int i = blockIdx.x*256 + threadIdx.x;   // BN
  const float* r = X + (size_t)i*C;
  float s = 0.f;
  #pragma unroll
  for(int c=0;c<C;c++) s = fmaf(r[c], r[c], s);
  xx[i] = s;
}

template<int C>
__launch_bounds__(256) __global__ void knn_part_k(const float* X, const float* xx,
                                                  float* pval, unsigned short* pidx){
  const int b = blockIdx.y;
  const int n = blockIdx.x*256 + threadIdx.x;
  const float* Xb = X + (size_t)b*NN*C;
  float xn[C];
  if constexpr (C % 4 == 0){
    #pragma unroll
    for(int c=0;c<C;c+=4){ float4 v = *(const float4*)(Xb + (size_t)n*C + c);
      xn[c]=v.x; xn[c+1]=v.y; xn[c+2]=v.z; xn[c+3]=v.w; }
  } else {
    #pragma unroll
    for(int c=0;c<C;c++) xn[c] = Xb[(size_t)n*C + c];
  }
  const float xxn = xx[b*NN+n];
  const float* xxb = xx + b*NN;
  float val[KK]; int ind[KK];
  #pragma unroll
  for(int j=0;j<KK;j++){ val[j] = -INFINITY; ind[j] = 0; }
  const int m0 = blockIdx.z*(NN/MSPLIT);
  #pragma unroll 2
  for(int m=m0; m<m0+NN/MSPLIT; ++m){
    float s = 0.f;
    if constexpr (C % 4 == 0){
      const float4* xm4 = (const float4*)(Xb + (size_t)m*C);
      #pragma unroll
      for(int c4=0;c4<C/4;c4++){
        float4 v = xm4[c4];
        s = fmaf(xn[4*c4+0], v.x, s); s = fmaf(xn[4*c4+1], v.y, s);
        s = fmaf(xn[4*c4+2], v.z, s); s = fmaf(xn[4*c4+3], v.w, s);
      }
    } else {
      const float* xm = Xb + (size_t)m*C;
      #pragma unroll
      for(int c=0;c<C;c++) s = fmaf(xn[c], xm[c], s);
    }
    float negd = (2.f*s - xxn) - xxb[m];
    if (negd > val[KK-1]){
      float cv = negd; int ci = m;
      #pragma unroll
      for(int j=0;j<KK;j++){
        if (cv > val[j]){ float tv=val[j]; int ti=ind[j]; val[j]=cv; ind[j]=ci; cv=tv; ci=ti; }
      }
    }
  }
  float*          pv = pval + (((size_t)(b*NN+n))*MSPLIT + blockIdx.z)*KK;
  unsigned short* pi = pidx + (((size_t)(b*NN+n))*MSPLIT + blockIdx.z)*KK;
  #pragma unroll
  for(int j=0;j<KK;j++){ pv[j]=val[j]; pi[j]=(unsigned short)ind[j]; }
}

__launch_bounds__(256) __global__ void knn_merge_k(const float* pval, const unsigned short* pidx, int* idx){
  int i = blockIdx.x*256 + threadIdx.x;   // BN
  const float* pv = pval + (size_t)i*MSPLIT*KK;
  const unsigned short* pi = pidx + (size_t)i*MSPLIT*KK;
  int* out = idx + (size_t)i*KK;
  float cv[MSPLIT]; int ci[MSPLIT]; int hp[MSPLIT];
  #pragma unroll
  for(int l=0;l<MSPLIT;l++){ cv[l]=pv[(size_t)l*KK]; ci[l]=pi[(size_t)l*KK]; hp[l]=1; }
  for(int j=0;j<KK;j++){
    float bv=-INFINITY; int bi=0x7fffffff; int bl=0;
    #pragma unroll
    for(int l=0;l<MSPLIT;l++){
      if (cv[l]>bv || (cv[l]==bv && ci[l]<bi)){ bv=cv[l]; bi=ci[l]; bl=l; }
    }
    out[j]=bi;
    if(hp[bl]<KK){ cv[bl]=pv[(size_t)bl*KK+hp[bl]]; ci[bl]=pi[(size_t)bl*KK+hp[bl]]; hp[bl]++; }
    else cv[bl]=-INFINITY;
  }
}

// ---------------- per-64-column qp + gather ----------------
// q[row,oi] = x_row . W[cb+oi, 0:CIN]; bs = (x_row . W[cb+oi, CIN:2CIN]) - q
template<int CIN>
__launch_bounds__(256) __global__ void qp64_k(const float* X, const float* W, int cb,
                                              float* q, float* bs){
  const int t   = blockIdx.x*256 + threadIdx.x;  // BN*8
  const int row = t >> 3;
  const int c0  = (t & 7) * 8;
  float xn[CIN];
  if constexpr (CIN % 4 == 0){
    #pragma unroll
    for(int c=0;c<CIN;c+=4){ float4 v = *(const float4*)(X + (size_t)row*CIN + c);
      xn[c]=v.x; xn[c+1]=v.y; xn[c+2]=v.z; xn[c+3]=v.w; }
  } else {
    #pragma unroll
    for(int c=0;c<CIN;c++) xn[c] = X[(size_t)row*CIN + c];
  }
  for(int oi=c0; oi<c0+8; oi++){
    const float* w = W + (size_t)(cb+oi)*2*CIN;
    float aq=0.f, ap=0.f;
    #pragma unroll
    for(int c=0;c<CIN;c++){ aq = fmaf(xn[c], w[c], aq); ap = fmaf(xn[c], w[CIN+c], ap); }
    q [(size_t)row*64 + oi] = aq;
    bs[(size_t)row*64 + oi] = ap - aq;
  }
}

template<int CFULL>
__launch_bounds__(256) __global__ void gather64_k(const float* q, const float* bs, const int* idx,
    const float* g, const float* bb, int cb, float* out){
  const int t  = blockIdx.x*256 + threadIdx.x;   // BN*64
  const int o  = t & 63;
  const int bn = t >> 6;
  const int b  = bn >> 11;
  const int* id = idx + (size_t)bn*KK;
  float base = bs[t];
  float mx = -INFINITY, mn = INFINITY;
  #pragma unroll
  for(int k=0;k<KK;k++){
    int ik = id[k];
    float v = q[((size_t)((b<<11) + ik))*64 + o];
    mx = fmaxf(mx, v); mn = fminf(mn, v);
  }
  float a  = g[cb+o] * RSQ;
  float bo = bb[cb+o];
  float h  = lrelu((a >= 0.f ? a*(mx+base) : a*(mn+base)) + bo);
  out[(size_t)bn*CFULL + cb + o] = h;
}

// ---------------- head: cat*W5^T with fused max/min over n ----------------
// LDS = 16*512*4 + 2*512*4 = 36864 B
__launch_bounds__(256) __global__ void w5max_k(const float* x1,const float* x2,const float* x3,
    const float* x4, const float* W5T, unsigned* mxe, unsigned* mne){
  __shared__ float cat[16*512];
  __shared__ float redm[512], redn[512];
  const int blk = blockIdx.x;             // 1024 = B * (N/16)
  const int b  = blk >> 7;
  const int r0 = (blk & 127)*16;
  const int t  = threadIdx.x;
  const size_t bn0 = (size_t)b*NN + r0;
  for(int i=t; i<16*512; i+=256){
    int r = i>>9, c = i&511;
    size_t row = bn0 + r;
    float v;
    if(c<64)       v = x1[row*64  + c];
    else if(c<128) v = x2[row*64  + (c-64)];
    else if(c<256) v = x3[row*128 + (c-128)];
    else           v = x4[row*256 + (c-256)];
    cat[i] = v;
  }
  __syncthreads();
  const int half = t>>7, tq = t&127;
  const int rbase = half*8;
  float acc[4][8];
  #pragma unroll
  for(int j=0;j<4;j++)
    #pragma unroll
    for(int r=0;r<8;r++) acc[j][r]=0.f;
  for(int c=0;c<512;c+=4){
    float w[4][4];
    #pragma unroll
    for(int cc=0;cc<4;cc++)
      #pragma unroll
      for(int j=0;j<4;j++) w[cc][j] = W5T[(size_t)(c+cc)*512 + tq + 128*j];
    #pragma unroll
    for(int r=0;r<8;r++){
      float4 cv = *(const float4*)&cat[(rbase+r)*512 + c];
      #pragma unroll
      for(int j=0;j<4;j++)
        acc[j][r] = fmaf(cv.x, w[0][j], fmaf(cv.y, w[1][j], fmaf(cv.z, w[2][j], fmaf(cv.w, w[3][j], acc[j][r]))));
    }
  }
  float lmx[4], lmn[4];
  #pragma unroll
  for(int j=0;j<4;j++){
    float M=-INFINITY, m=INFINITY;
    #pragma unroll
    for(int r=0;r<8;r++){ M=fmaxf(M,acc[j][r]); m=fminf(m,acc[j][r]); }
    lmx[j]=M; lmn[j]=m;
  }
  if(half==0){
    #pragma unroll
    for(int j=0;j<4;j++){ redm[tq+128*j]=lmx[j]; redn[tq+128*j]=lmn[j]; }
  }
  __syncthreads();
  if(half==1){
    #pragma unroll
    for(int j=0;j<4;j++){
      int o = tq + 128*j;
      float M = fmaxf(lmx[j], redm[o]);
      float m = fminf(lmn[j], redn[o]);
      atomicMax(&mxe[b*512+o], encf(M));
      atomicMin(&mne[b*512+o], encf(m));
    }
  }
}

__launch_bounds__(256) __global__ void final_k(const unsigned* mxe, const unsigned* mne,
    const float* g5, const float* b5, const float* Wemb, float* out){
  const int b = blockIdx.x, t = threadIdx.x;
  __shared__ float h[512];
  for(int o=t; o<512; o+=256){
    float mx = decf(mxe[b*512+o]);
    float mn = decf(mne[b*512+o]);
    float a  = g5[o] * RSQ;
    float bo = b5[o];
    float hv = lrelu((a >= 0.f ? a*mx : a*mn) + bo);
    h[o] = hv;
    out[b*512+o] = hv;                       // feat (B,1,512)
  }
  __syncthreads();
  const float* wr = Wemb + (size_t)t*512;
  float s = 0.f;
  for(int o=0;o<512;o+=4){
    float4 w4 = *(const float4*)(wr+o);
    s = fmaf(h[o],w4.x, fmaf(h[o+1],w4.y, fmaf(h[o+2],w4.z, fmaf(h[o+3],w4.w, s))));
  }
  out[4096 + b*256 + t] = s;                 // embedding (B,256)
}

// ---------------- launch ----------------
extern "C" void kernel_launch(void* const* d_in, const int* in_sizes, int n_in,
                              void* d_out, int out_size, void* d_ws, size_t ws_size,
                              hipStream_t stream) {
  if (ws_size < WS_END * sizeof(float)) return;   // diagnostic guard

  const float* x0   = (const float*)d_in[0];
  const float* W1   = (const float*)d_in[1];
  const float* g1   = (const float*)d_in[2];
  const float* b1   = (const float*)d_in[3];
  const float* W2   = (const float*)d_in[4];
  const float* g2   = (const float*)d_in[5];
  const float* b2   = (const float*)d_in[6];
  const float* W3   = (const float*)d_in[7];
  const float* g3   = (const float*)d_in[8];
  const float* b3   = (const float*)d_in[9];
  const float* W4   = (const float*)d_in[10];
  const float* g4   = (const float*)d_in[11];
  const float* b4   = (const float*)d_in[12];
  const float* W5   = (const float*)d_in[13];
  const float* g5   = (const float*)d_in[14];
  const float* b5   = (const float*)d_in[15];
  const float* Wemb = (const float*)d_in[16];

  float* ws = (float*)d_ws;
  float* x1 = ws + OFF_X1;  float* x2 = ws + OFF_X2;
  float* x3 = ws + OFF_X3;  float* x4 = ws + OFF_X4;
  float* xx = ws + OFF_XX;
  // pv/pi alias into x4: x4 is only written by layer-4's gather (after layer-4 merge)
  // and read by w5max (after that) -> dead during every knn_part/knn_merge phase.
  // pv: BN*MSPLIT*KK floats (2.62M) ; pi: BN*MSPLIT*KK ushorts (1.31M slots) ; total 3.93M <= BN*256
  float*          pv = ws + OFF_X4;
  unsigned short* pi = (unsigned short*)(ws + OFF_X4 + (size_t)BN*MSPLIT*KK);
  float* q  = ws + OFF_SC;
  float* bs = ws + OFF_SC + (size_t)BN*64;
  int*   id = (int*)(ws + OFF_ID);
  float* W5Tf = ws + OFF_W5T;
  unsigned* mxe = (unsigned*)(ws + OFF_MX);
  unsigned* mne = (unsigned*)(ws + OFF_MN);
  float* out = (float*)d_out;

  transposeW5_k<<<262144/256,256,0,stream>>>(W5, W5Tf);
  init_enc_k<<<BB*512/256,256,0,stream>>>(mxe, mne);

  dim3 kgrid(NN/256, BB, MSPLIT);

  // layer 1 (3 -> 64)
  sqnorm_k<3><<<BN/256,256,0,stream>>>(x0, xx);
  knn_part_k<3><<<kgrid,256,0,stream>>>(x0, xx, pv, pi);
  knn_merge_k<<<BN/256,256,0,stream>>>(pv, pi, id);
  qp64_k<3><<<BN*8/256,256,0,stream>>>(x0, W1, 0, q, bs);
  gather64_k<64><<<BN*64/256,256,0,stream>>>(q, bs, id, g1, b1, 0, x1);

  // layer 2 (64 -> 64)
  sqnorm_k<64><<<BN/256,256,0,stream>>>(x1, xx);
  knn_part_k<64><<<kgrid,256,0,stream>>>(x1, xx, pv, pi);
  knn_merge_k<<<BN/256,256,0,stream>>>(pv, pi, id);
  qp64_k<64><<<BN*8/256,256,0,stream>>>(x1, W2, 0, q, bs);
  gather64_k<64><<<BN*64/256,256,0,stream>>>(q, bs, id, g2, b2, 0, x2);

  // layer 3 (64 -> 128)
  sqnorm_k<64><<<BN/256,256,0,stream>>>(x2, xx);
  knn_part_k<64><<<kgrid,256,0,stream>>>(x2, xx, pv, pi);
  knn_merge_k<<<BN/256,256,0,stream>>>(pv, pi, id);
  for(int cb=0; cb<128; cb+=64){
    qp64_k<64><<<BN*8/256,256,0,stream>>>(x2, W3, cb, q, bs);
    gather64_k<128><<<BN*64/256,256,0,stream>>>(q, bs, id, g3, b3, cb, x3);
  }

  // layer 4 (128 -> 256)
  sqnorm_k<128><<<BN/256,256,0,stream>>>(x3, xx);
  knn_part_k<128><<<kgrid,256,0,stream>>>(x3, xx, pv, pi);
  knn_merge_k<<<BN/256,256,0,stream>>>(pv, pi, id);
  for(int cb=0; cb<256; cb+=64){
    qp64_k<128><<<BN*8/256,256,0,stream>>>(x3, W4, cb, q, bs);
    gather64_k<256><<<BN*64/256,256,0,stream>>>(q, bs, id, g4, b4, cb, x4);
  }

  // head
  w5max_k<<<BB*(NN/16),256,0,stream>>>(x1, x2, x3, x4, W5Tf, mxe, mne);
  final_k<<<BB,256,0,stream>>>(mxe, mne, g5, b5, Wemb, out);
}